// Round 1
// baseline (506.305 us; speedup 1.0000x reference)
//
#include <hip/hip_runtime.h>
#include <stdint.h>
#include <stddef.h>

#define HIN 128
#define WIN 128
#define CINC 64
#define COUTC 128
#define HO 126
#define WO 126
#define HP 63
#define WP 63
#define NB 32
#define NG 16

typedef __bf16 bf16x8 __attribute__((ext_vector_type(8)));
typedef float f32x16 __attribute__((ext_vector_type(16)));

__device__ __forceinline__ unsigned int f2bf(float f) {
  unsigned int u = __float_as_uint(f);
  return (u + 0x7fffu + ((u >> 16) & 1u)) >> 16;   // RNE
}

// ---- weights: w[co][cin][kh][kw] fp32 -> wt2[(tap*4+ks)*2+half][co][8] bf16 ----
// linear per-tap blocks of 16384 B; L2-resident (147 KB total), read by all blocks.
__global__ __launch_bounds__(256) void wtrans_k(const float* __restrict__ w,
                                                unsigned short* __restrict__ wt2) {
  int i = blockIdx.x * 256 + threadIdx.x;
  if (i >= 73728) return;
  int j = i & 7;
  int co = (i >> 3) & 127;
  int th = i >> 10;                 // [0,72)
  int half = th & 1, ks = (th >> 1) & 3, tap = th >> 3;
  int kh = tap / 3, kw = tap - 3 * kh;
  int cin = ks * 16 + half * 8 + j;
  float v = w[((co * CINC + cin) * 3 + kh) * 3 + kw];
  wt2[i] = (unsigned short)f2bf(v);
}

// ---- conv implicit-GEMM ----
// grid: (64 tiles = 8 th x 8 tw, 32 batch), block 256 = 4 waves.
// Block tile 256 px (16x16) x 128 co; wave = 64 px x 128 co (mt2 x nt4).
// R5 change: B-operands (weights) no longer staged in LDS. They are L2-resident
// (147 KB broadcast to all 2048 blocks); each wave ping-pong prefetches the next
// tap's 16 uint4 fragments into registers one tap ahead. This removes aux_lds
// (LDS 75264 -> 41472 B => 3 blocks/CU instead of 2) and removes ALL 9 main-loop
// barriers (x_lds is read-only during the K-loop; weight sync is just the
// compiler's vmcnt wait on first register use). Pooled 2x2 routing reuses x_lds
// after a barrier. Raw-max-before-affine valid: A = rstd*gn_w*scale > 0.
__global__ __launch_bounds__(256, 3) void conv_k(const float* __restrict__ x,
                                                 const unsigned short* __restrict__ wt2,
                                                 const float* __restrict__ conv_b,
                                                 float* __restrict__ out,
                                                 float* __restrict__ stats) {
  __shared__ __align__(16) unsigned int x_lds[18 * 18 * 32];  // 41472 B, XOR-swizzled

  int t = threadIdx.x;
  int lane = t & 63, wave = t >> 6;
  int tw = blockIdx.x & 7, th = blockIdx.x >> 3;
  int b = blockIdx.y;
  int oh0 = th * 16, ow0 = tw * 16;
  int half = lane >> 5, m = lane & 31;

  // ---- weight register prefetch: tap 0 issued before x staging (overlaps) ----
  const uint4* wg4 = (const uint4*)wt2;  // uint4 idx = tap*1024 + ks*256 + half*128 + nt*32 + m
  uint4 wA[16], wB[16];
#pragma unroll
  for (int i = 0; i < 16; ++i)
    wA[i] = wg4[(i >> 2) * 256 + half * 128 + (i & 3) * 32 + m];

  // ---- x staging: fp32 NCHW -> bf16 ci-pair dwords, swizzle d = p ^ ((c&7)<<2) ----
  const float* xb = x + (size_t)b * CINC * HIN * WIN;
  for (int i = t; i < 2880; i += 256) {       // 5 c4 x 32 cipair x 18 r
    int c4 = i % 5;
    int j = i / 5;
    int p = j & 31;            // cipair: ci = 2p, 2p+1
    int r = j >> 5;            // 0..17
    int gr = oh0 + r;
    int gc0 = ow0 + c4 * 4;
    float4 v0 = make_float4(0.f, 0.f, 0.f, 0.f);
    float4 v1 = v0;
    if (gr < HIN && gc0 < WIN) {
      const float* base = xb + ((size_t)(2 * p) * HIN + gr) * WIN + gc0;
      v0 = *(const float4*)base;
      v1 = *(const float4*)(base + HIN * WIN);
    }
    float e0[4] = {v0.x, v0.y, v0.z, v0.w};
    float e1[4] = {v1.x, v1.y, v1.z, v1.w};
#pragma unroll
    for (int cc = 0; cc < 4; ++cc) {
      int c = c4 * 4 + cc;
      if (c < 18) {
        unsigned int d = f2bf(e0[cc]) | (f2bf(e1[cc]) << 16);
        x_lds[(r * 18 + c) * 32 + (p ^ ((c & 7) << 2))] = d;
      }
    }
  }
  __syncthreads();   // x ready; only barrier before the epilogue

  // ---- MFMA main loop (no barriers; weights ping-pong in registers) ----
  f32x16 acc[2][4];
#pragma unroll
  for (int nt = 0; nt < 4; ++nt) {
    float bias = conv_b[nt * 32 + m];
#pragma unroll
    for (int mt = 0; mt < 2; ++mt)
#pragma unroll
      for (int r = 0; r < 16; ++r) acc[mt][nt][r] = bias;
  }

  int prb = wave * 4 + (m >> 4);   // + mt*2 + kh  -> pixel row in 18
  int pcc = m & 15;                // + kw         -> pixel col in 18

#define CONV_TAP(tap, cur, nxt)                                                \
  {                                                                            \
    if ((tap) < 8) {                                                           \
      _Pragma("unroll")                                                        \
      for (int i = 0; i < 16; ++i)                                             \
        nxt[i] = wg4[((tap) + 1) * 1024 + (i >> 2) * 256 + half * 128 +        \
                     (i & 3) * 32 + m];                                        \
    }                                                                          \
    const int kh = (tap) / 3, kw = (tap) - 3 * ((tap) / 3);                    \
    int c = pcc + kw;                                                          \
    int swz = (c & 7) << 2;                                                    \
    _Pragma("unroll")                                                          \
    for (int ks = 0; ks < 4; ++ks) {                                           \
      int ab = c * 32 + ((ks * 8 + half * 4) ^ swz);                           \
      bf16x8 afr[2];                                                           \
      _Pragma("unroll")                                                        \
      for (int mt = 0; mt < 2; ++mt)                                           \
        afr[mt] = __builtin_bit_cast(                                          \
            bf16x8, *(const uint4*)&x_lds[(prb + mt * 2 + kh) * 576 + ab]);    \
      _Pragma("unroll")                                                        \
      for (int nt = 0; nt < 4; ++nt) {                                         \
        bf16x8 bfr = __builtin_bit_cast(bf16x8, cur[ks * 4 + nt]);             \
        _Pragma("unroll")                                                      \
        for (int mt = 0; mt < 2; ++mt)                                         \
          acc[mt][nt] = __builtin_amdgcn_mfma_f32_32x32x16_bf16(               \
              afr[mt], bfr, acc[mt][nt], 0, 0, 0);                             \
      }                                                                        \
    }                                                                          \
  }

  CONV_TAP(0, wA, wB)
  CONV_TAP(1, wB, wA)
  CONV_TAP(2, wA, wB)
  CONV_TAP(3, wB, wA)
  CONV_TAP(4, wA, wB)
  CONV_TAP(5, wB, wA)
  CONV_TAP(6, wA, wB)
  CONV_TAP(7, wB, wA)
  CONV_TAP(8, wA, wB)
#undef CONV_TAP

  // ---- GN partial sums (verified C/D mapping: row=pixel, col=cout) ----
  float s[4] = {0.f, 0.f, 0.f, 0.f}, qs[4] = {0.f, 0.f, 0.f, 0.f};
#pragma unroll
  for (int nt = 0; nt < 4; ++nt) {
#pragma unroll
    for (int mt = 0; mt < 2; ++mt) {
#pragma unroll
      for (int reg = 0; reg < 16; ++reg) {
        int c16 = (reg & 3) + 4 * half + 8 * ((reg >> 2) & 1);  // pixel col in 16
        int r8 = wave * 4 + mt * 2 + (reg >> 3);                // pixel row in 16
        if ((oh0 + r8) < HO && (ow0 + c16) < WO) {
          float v = acc[mt][nt][reg];
          s[nt] += v;
          qs[nt] += v * v;
        }
      }
    }
  }
#pragma unroll
  for (int nt = 0; nt < 4; ++nt) {
    float sv = s[nt], qv = qs[nt];
    sv += __shfl_xor(sv, 32);
    qv += __shfl_xor(qv, 32);
    sv += __shfl_down(sv, 4, 8);
    qv += __shfl_down(qv, 4, 8);
    sv += __shfl_down(sv, 2, 8);
    qv += __shfl_down(qv, 2, 8);
    sv += __shfl_down(sv, 1, 8);
    qv += __shfl_down(qv, 1, 8);
    if (half == 0 && (m & 7) == 0) {
      int g = nt * 4 + (m >> 3);
      atomicAdd(&stats[(b * NG + g) * 2 + 0], sv);
      atomicAdd(&stats[(b * NG + g) * 2 + 1], qv);
    }
  }

  __syncthreads();   // all waves done reading x_lds -> safe to reuse for pooled

  // ---- pooled 2x2 raw max -> x_lds (stride 66 dw/co: 2-way banks, free) ----
#pragma unroll
  for (int nt = 0; nt < 4; ++nt) {
    int co = nt * 32 + m;
#pragma unroll
    for (int mt = 0; mt < 2; ++mt) {
      int oh2l = wave * 2 + mt;
#pragma unroll
      for (int i = 0; i < 4; ++i) {
        int r0 = 2 * i;
        int ow2l = (i & 1) + 2 * half + 4 * (i >> 1);
        float mx = fmaxf(fmaxf(acc[mt][nt][r0], acc[mt][nt][r0 + 1]),
                         fmaxf(acc[mt][nt][r0 + 8], acc[mt][nt][r0 + 9]));
        x_lds[co * 66 + oh2l * 8 + ow2l] = __float_as_uint(mx);
      }
    }
  }
  __syncthreads();

  // ---- readback: 4 rows/thread, 8 consecutive dwords per row ----
#pragma unroll
  for (int i = 0; i < 4; ++i) {
    int row = t * 4 + i;           // row = co*8 + oh2l
    int co = row >> 3, oh2l = row & 7;
    int oh2 = th * 8 + oh2l;
    if (oh2 < HP) {
      const uint2* src = (const uint2*)&x_lds[co * 66 + oh2l * 8];
      uint2 d0 = src[0], d1 = src[1], d2 = src[2], d3 = src[3];
      unsigned int v[8] = {d0.x, d0.y, d1.x, d1.y, d2.x, d2.y, d3.x, d3.y};
      float* ob = out + ((size_t)(b * COUTC + co) * HP + oh2) * WP + tw * 8;
      int n = (tw == 7) ? 7 : 8;   // WP = 63
#pragma unroll
      for (int e = 0; e < 8; ++e)
        if (e < n) ob[e] = __uint_as_float(v[e]);
    }
  }
}

// ---- finalize: one block per (b,c) plane; A,B computed once, pure streaming ----
__global__ __launch_bounds__(256) void fin_k(float* __restrict__ out,
                                             const float* __restrict__ stats,
                                             const float* __restrict__ gn_w,
                                             const float* __restrict__ gn_b,
                                             const float* __restrict__ scale) {
  const int plane = HP * WP;                     // 3969 (odd -> plane bases rotate mod 4)
  const float inv_cnt = 1.0f / (8.0f * HO * WO);
  int bc = blockIdx.x;                           // b*128 + c, grid = 4096
  int c = bc & 127, b = bc >> 7;
  int g = c >> 3;
  float su = stats[(b * NG + g) * 2 + 0];
  float sq = stats[(b * NG + g) * 2 + 1];
  float mean = su * inv_cnt;
  float var = fmaxf(sq * inv_cnt - mean * mean, 0.f);
  float rstd = rsqrtf(var + 1e-5f);
  float gw = gn_w[c], sc = scale[c];
  float A = rstd * gw * sc;
  float Bo = (gn_b[c] - mean * rstd * gw) * sc;

  float* p = out + (size_t)bc * plane;
  int t = threadIdx.x;
  int head = (4 - (bc & 3)) & 3;                 // scalars until 16B-aligned
  if (t < head) p[t] = fminf(fmaxf(fmaf(p[t], A, Bo), 0.0f), 1.0f);
  int n4 = (plane - head) >> 2;
  float4* p4 = (float4*)(p + head);
  for (int i = t; i < n4; i += 256) {
    float4 v = p4[i];
    v.x = fminf(fmaxf(fmaf(v.x, A, Bo), 0.0f), 1.0f);
    v.y = fminf(fmaxf(fmaf(v.y, A, Bo), 0.0f), 1.0f);
    v.z = fminf(fmaxf(fmaf(v.z, A, Bo), 0.0f), 1.0f);
    v.w = fminf(fmaxf(fmaf(v.w, A, Bo), 0.0f), 1.0f);
    p4[i] = v;
  }
  int done = head + (n4 << 2);
  int tail = plane - done;                       // 0..3
  if (t < tail) p[done + t] = fminf(fmaxf(fmaf(p[done + t], A, Bo), 0.0f), 1.0f);
}

// ---- launch ----
extern "C" void kernel_launch(void* const* d_in, const int* in_sizes, int n_in,
                              void* d_out, int out_size, void* d_ws, size_t ws_size,
                              hipStream_t stream) {
  const float* x      = (const float*)d_in[0];
  const float* conv_w = (const float*)d_in[1];
  const float* conv_b = (const float*)d_in[2];
  const float* gn_w   = (const float*)d_in[3];
  const float* gn_b   = (const float*)d_in[4];
  const float* scale  = (const float*)d_in[5];
  float* out = (float*)d_out;

  float* stats        = (float*)d_ws;                           // 4 KB
  unsigned short* wt2 = (unsigned short*)((char*)d_ws + 4096);  // 147456 B

  hipMemsetAsync(d_ws, 0, 4096, stream);
  wtrans_k<<<288, 256, 0, stream>>>(conv_w, wt2);

  conv_k<<<dim3(64, NB), 256, 0, stream>>>(x, wt2, conv_b, out, stats);

  fin_k<<<NB * COUTC, 256, 0, stream>>>(out, stats, gn_w, gn_b, scale);
}

// Round 2
// 494.084 us; speedup vs baseline: 1.0247x; 1.0247x over previous
//
#include <hip/hip_runtime.h>
#include <stdint.h>
#include <stddef.h>

#define HIN 128
#define WIN 128
#define CINC 64
#define COUTC 128
#define HO 126
#define WO 126
#define HP 63
#define WP 63
#define NB 32
#define NG 16

typedef __bf16 bf16x8 __attribute__((ext_vector_type(8)));
typedef float f32x16 __attribute__((ext_vector_type(16)));

__device__ __forceinline__ unsigned int f2bf(float f) {
  unsigned int u = __float_as_uint(f);
  return (u + 0x7fffu + ((u >> 16) & 1u)) >> 16;   // RNE
}

// ---- weights: w[co][cin][kh][kw] fp32 -> wt2[(tap*4+ks)*2+half][co][8] bf16 ----
// linear per-step blocks of 4096 B; L2-resident (147 KB total), read by all blocks.
__global__ __launch_bounds__(256) void wtrans_k(const float* __restrict__ w,
                                                unsigned short* __restrict__ wt2) {
  int i = blockIdx.x * 256 + threadIdx.x;
  if (i >= 73728) return;
  int j = i & 7;
  int co = (i >> 3) & 127;
  int th = i >> 10;                 // [0,72)
  int half = th & 1, ks = (th >> 1) & 3, tap = th >> 3;
  int kh = tap / 3, kw = tap - 3 * kh;
  int cin = ks * 16 + half * 8 + j;
  float v = w[((co * CINC + cin) * 3 + kh) * 3 + kw];
  wt2[i] = (unsigned short)f2bf(v);
}

// ---- conv implicit-GEMM ----
// grid: (64 tiles = 8 th x 8 tw, 32 batch), block 256 = 4 waves.
// Block tile 256 px (16x16) x 128 co; wave = 64 px x 128 co (mt2 x nt4).
// R2: B-operands come from L2 (147 KB weight set is resident) straight into
// registers, prefetched ONE ks-step ahead (4+4 uint4 = 32 VGPRs in flight --
// R1's 128-reg version spilled under launch_bounds(256,3)). Ping-pong is by
// unroll parity, so no register copies and no vmcnt collapse. Main loop has
// ZERO barriers: x_lds is read-only after staging, weights are per-wave regs.
// launch_bounds(256,2): 256-reg budget = 128 acc + ~64 arch, no spill.
// Occupancy 2 blocks/CU (LDS would allow 3; regs cap at 2 -- acc alone forbids
// 3/SIMD). Win comes from stall removal: no per-tap vmcnt(0) drains, LDS pipe
// load cut from 24 to 8 ds_read_b128 per tap per wave.
// Pooled epilogue reuses x_lds. Raw-max-before-affine valid: A>0.
__global__ __launch_bounds__(256, 2) void conv_k(const float* __restrict__ x,
                                                 const unsigned short* __restrict__ wt2,
                                                 const float* __restrict__ conv_b,
                                                 float* __restrict__ out,
                                                 float* __restrict__ stats) {
  __shared__ __align__(16) unsigned int x_lds[18 * 18 * 32];  // 41472 B, XOR-swizzled

  int t = threadIdx.x;
  int lane = t & 63, wave = t >> 6;
  int tw = blockIdx.x & 7, th = blockIdx.x >> 3;
  int b = blockIdx.y;
  int oh0 = th * 16, ow0 = tw * 16;
  int half = lane >> 5, m = lane & 31;

  // lane-fixed weight base: uint4 idx = s*256 + nt*32 + (half*128 + m)
  const uint4* wpl = (const uint4*)wt2 + half * 128 + m;

  // step-0 weights issued before x staging (L2 latency hidden under staging)
  uint4 wA[4], wB[4];
#pragma unroll
  for (int nt = 0; nt < 4; ++nt) wA[nt] = wpl[nt * 32];

  // per-wave bias, also early
  float bias[4];
#pragma unroll
  for (int nt = 0; nt < 4; ++nt) bias[nt] = conv_b[nt * 32 + m];

  // ---- x staging: fp32 NCHW -> bf16 ci-pair dwords, swizzle d = p ^ ((c&7)<<2) ----
  // constant trip count (12, last masked) + full unroll -> loads batch in flight
  const float* xb = x + (size_t)b * CINC * HIN * WIN;
#pragma unroll
  for (int k = 0; k < 12; ++k) {
    int i = k * 256 + t;
    if (i < 2880) {            // 5 c4 x 32 cipair x 18 r
      int c4 = i % 5;
      int j = i / 5;
      int p = j & 31;          // cipair: ci = 2p, 2p+1
      int r = j >> 5;          // 0..17
      int gr = oh0 + r;
      int gc0 = ow0 + c4 * 4;
      float4 v0 = make_float4(0.f, 0.f, 0.f, 0.f);
      float4 v1 = v0;
      if (gr < HIN && gc0 < WIN) {
        const float* base = xb + ((size_t)(2 * p) * HIN + gr) * WIN + gc0;
        v0 = *(const float4*)base;
        v1 = *(const float4*)(base + HIN * WIN);
      }
      float e0[4] = {v0.x, v0.y, v0.z, v0.w};
      float e1[4] = {v1.x, v1.y, v1.z, v1.w};
#pragma unroll
      for (int cc = 0; cc < 4; ++cc) {
        int c = c4 * 4 + cc;
        if (c < 18) {
          unsigned int d = f2bf(e0[cc]) | (f2bf(e1[cc]) << 16);
          x_lds[(r * 18 + c) * 32 + (p ^ ((c & 7) << 2))] = d;
        }
      }
    }
  }
  __syncthreads();   // x ready; the ONLY pre-epilogue barrier

  // ---- MFMA main loop (no barriers; 1-step weight ping-pong in registers) ----
  f32x16 acc[2][4];
#pragma unroll
  for (int nt = 0; nt < 4; ++nt)
#pragma unroll
    for (int mt = 0; mt < 2; ++mt)
#pragma unroll
      for (int r = 0; r < 16; ++r) acc[mt][nt][r] = bias[nt];

  int prb = wave * 4 + (m >> 4);   // + mt*2 + kh  -> pixel row in 18
  int pcc = m & 15;                // + kw         -> pixel col in 18

#define CONV_STEP(s_, cur, nxt)                                                \
  {                                                                            \
    if ((s_) < 35) {                                                           \
      _Pragma("unroll")                                                        \
      for (int nt = 0; nt < 4; ++nt)                                           \
        nxt[nt] = wpl[((s_) + 1) * 256 + nt * 32];                             \
    }                                                                          \
    const int tap_ = (s_) >> 2, ks_ = (s_)&3;                                  \
    const int kh_ = tap_ / 3, kw_ = tap_ - 3 * kh_;                            \
    int c_ = pcc + kw_;                                                        \
    int swz_ = (c_ & 7) << 2;                                                  \
    int ab_ = c_ * 32 + ((ks_ * 8 + half * 4) ^ swz_);                         \
    bf16x8 afr[2];                                                             \
    _Pragma("unroll")                                                          \
    for (int mt = 0; mt < 2; ++mt)                                             \
      afr[mt] = __builtin_bit_cast(                                            \
          bf16x8, *(const uint4*)&x_lds[(prb + mt * 2 + kh_) * 576 + ab_]);    \
    _Pragma("unroll")                                                          \
    for (int nt = 0; nt < 4; ++nt) {                                           \
      bf16x8 bfr = __builtin_bit_cast(bf16x8, cur[nt]);                        \
      _Pragma("unroll")                                                        \
      for (int mt = 0; mt < 2; ++mt)                                           \
        acc[mt][nt] = __builtin_amdgcn_mfma_f32_32x32x16_bf16(                 \
            afr[mt], bfr, acc[mt][nt], 0, 0, 0);                               \
    }                                                                          \
  }

#pragma unroll
  for (int tap = 0; tap < 9; ++tap) {
    CONV_STEP(tap * 4 + 0, wA, wB)
    CONV_STEP(tap * 4 + 1, wB, wA)
    CONV_STEP(tap * 4 + 2, wA, wB)
    CONV_STEP(tap * 4 + 3, wB, wA)
  }
#undef CONV_STEP

  // ---- GN partial sums (verified C/D mapping: row=pixel, col=cout) ----
  float s[4] = {0.f, 0.f, 0.f, 0.f}, qs[4] = {0.f, 0.f, 0.f, 0.f};
#pragma unroll
  for (int nt = 0; nt < 4; ++nt) {
#pragma unroll
    for (int mt = 0; mt < 2; ++mt) {
#pragma unroll
      for (int reg = 0; reg < 16; ++reg) {
        int c16 = (reg & 3) + 4 * half + 8 * ((reg >> 2) & 1);  // pixel col in 16
        int r8 = wave * 4 + mt * 2 + (reg >> 3);                // pixel row in 16
        if ((oh0 + r8) < HO && (ow0 + c16) < WO) {
          float v = acc[mt][nt][reg];
          s[nt] += v;
          qs[nt] += v * v;
        }
      }
    }
  }
#pragma unroll
  for (int nt = 0; nt < 4; ++nt) {
    float sv = s[nt], qv = qs[nt];
    sv += __shfl_xor(sv, 32);
    qv += __shfl_xor(qv, 32);
    sv += __shfl_down(sv, 4, 8);
    qv += __shfl_down(qv, 4, 8);
    sv += __shfl_down(sv, 2, 8);
    qv += __shfl_down(qv, 2, 8);
    sv += __shfl_down(sv, 1, 8);
    qv += __shfl_down(qv, 1, 8);
    if (half == 0 && (m & 7) == 0) {
      int g = nt * 4 + (m >> 3);
      atomicAdd(&stats[(b * NG + g) * 2 + 0], sv);
      atomicAdd(&stats[(b * NG + g) * 2 + 1], qv);
    }
  }

  __syncthreads();   // all waves done reading x_lds -> safe to reuse for pooled

  // ---- pooled 2x2 raw max -> x_lds (stride 66 dw/co: 2-way banks, free) ----
#pragma unroll
  for (int nt = 0; nt < 4; ++nt) {
    int co = nt * 32 + m;
#pragma unroll
    for (int mt = 0; mt < 2; ++mt) {
      int oh2l = wave * 2 + mt;
#pragma unroll
      for (int i = 0; i < 4; ++i) {
        int r0 = 2 * i;
        int ow2l = (i & 1) + 2 * half + 4 * (i >> 1);
        float mx = fmaxf(fmaxf(acc[mt][nt][r0], acc[mt][nt][r0 + 1]),
                         fmaxf(acc[mt][nt][r0 + 8], acc[mt][nt][r0 + 9]));
        x_lds[co * 66 + oh2l * 8 + ow2l] = __float_as_uint(mx);
      }
    }
  }
  __syncthreads();

  // ---- readback: 4 rows/thread, 8 consecutive dwords per row ----
#pragma unroll
  for (int i = 0; i < 4; ++i) {
    int row = t * 4 + i;           // row = co*8 + oh2l
    int co = row >> 3, oh2l = row & 7;
    int oh2 = th * 8 + oh2l;
    if (oh2 < HP) {
      const uint2* src = (const uint2*)&x_lds[co * 66 + oh2l * 8];
      uint2 d0 = src[0], d1 = src[1], d2 = src[2], d3 = src[3];
      unsigned int v[8] = {d0.x, d0.y, d1.x, d1.y, d2.x, d2.y, d3.x, d3.y};
      float* ob = out + ((size_t)(b * COUTC + co) * HP + oh2) * WP + tw * 8;
      int n = (tw == 7) ? 7 : 8;   // WP = 63
#pragma unroll
      for (int e = 0; e < 8; ++e)
        if (e < n) ob[e] = __uint_as_float(v[e]);
    }
  }
}

// ---- finalize: one block per (b,c) plane; A,B computed once, pure streaming ----
__global__ __launch_bounds__(256) void fin_k(float* __restrict__ out,
                                             const float* __restrict__ stats,
                                             const float* __restrict__ gn_w,
                                             const float* __restrict__ gn_b,
                                             const float* __restrict__ scale) {
  const int plane = HP * WP;                     // 3969 (odd -> plane bases rotate mod 4)
  const float inv_cnt = 1.0f / (8.0f * HO * WO);
  int bc = blockIdx.x;                           // b*128 + c, grid = 4096
  int c = bc & 127, b = bc >> 7;
  int g = c >> 3;
  float su = stats[(b * NG + g) * 2 + 0];
  float sq = stats[(b * NG + g) * 2 + 1];
  float mean = su * inv_cnt;
  float var = fmaxf(sq * inv_cnt - mean * mean, 0.f);
  float rstd = rsqrtf(var + 1e-5f);
  float gw = gn_w[c], sc = scale[c];
  float A = rstd * gw * sc;
  float Bo = (gn_b[c] - mean * rstd * gw) * sc;

  float* p = out + (size_t)bc * plane;
  int t = threadIdx.x;
  int head = (4 - (bc & 3)) & 3;                 // scalars until 16B-aligned
  if (t < head) p[t] = fminf(fmaxf(fmaf(p[t], A, Bo), 0.0f), 1.0f);
  int n4 = (plane - head) >> 2;
  float4* p4 = (float4*)(p + head);
  for (int i = t; i < n4; i += 256) {
    float4 v = p4[i];
    v.x = fminf(fmaxf(fmaf(v.x, A, Bo), 0.0f), 1.0f);
    v.y = fminf(fmaxf(fmaf(v.y, A, Bo), 0.0f), 1.0f);
    v.z = fminf(fmaxf(fmaf(v.z, A, Bo), 0.0f), 1.0f);
    v.w = fminf(fmaxf(fmaf(v.w, A, Bo), 0.0f), 1.0f);
    p4[i] = v;
  }
  int done = head + (n4 << 2);
  int tail = plane - done;                       // 0..3
  if (t < tail) p[done + t] = fminf(fmaxf(fmaf(p[done + t], A, Bo), 0.0f), 1.0f);
}

// ---- launch ----
extern "C" void kernel_launch(void* const* d_in, const int* in_sizes, int n_in,
                              void* d_out, int out_size, void* d_ws, size_t ws_size,
                              hipStream_t stream) {
  const float* x      = (const float*)d_in[0];
  const float* conv_w = (const float*)d_in[1];
  const float* conv_b = (const float*)d_in[2];
  const float* gn_w   = (const float*)d_in[3];
  const float* gn_b   = (const float*)d_in[4];
  const float* scale  = (const float*)d_in[5];
  float* out = (float*)d_out;

  float* stats        = (float*)d_ws;                           // 4 KB
  unsigned short* wt2 = (unsigned short*)((char*)d_ws + 4096);  // 147456 B

  hipMemsetAsync(d_ws, 0, 4096, stream);
  wtrans_k<<<288, 256, 0, stream>>>(conv_w, wt2);

  conv_k<<<dim3(64, NB), 256, 0, stream>>>(x, wt2, conv_b, out, stats);

  fin_k<<<4096, 256, 0, stream>>>(out, stats, gn_w, gn_b, scale);
}

// Round 3
// 379.435 us; speedup vs baseline: 1.3344x; 1.3022x over previous
//
#include <hip/hip_runtime.h>
#include <stdint.h>
#include <stddef.h>

#define HIN 128
#define WIN 128
#define CINC 64
#define COUTC 128
#define HO 126
#define WO 126
#define HP 63
#define WP 63
#define NB 32
#define NG 16

typedef __bf16 bf16x8 __attribute__((ext_vector_type(8)));
typedef float f32x16 __attribute__((ext_vector_type(16)));

#define AS1U(p) ((const __attribute__((address_space(1))) unsigned int*)(p))
#define AS3U(p) ((__attribute__((address_space(3))) unsigned int*)(p))

__device__ __forceinline__ unsigned int f2bf(float f) {
  unsigned int u = __float_as_uint(f);
  return (u + 0x7fffu + ((u >> 16) & 1u)) >> 16;   // RNE
}

// ---- weights: w[co][cin][kh][kw] fp32 -> wt2[(tap*4+ks)*2+half][co][8] bf16 ----
// linear per-step blocks of 4096 B; L2-resident (147 KB), read once per block
// per half-tap via global_load_lds DMA. Also zeroes the stats workspace
// (saves the separate memset dispatch).
__global__ __launch_bounds__(256) void wtrans_k(const float* __restrict__ w,
                                                unsigned short* __restrict__ wt2,
                                                float* __restrict__ stats) {
  int i = blockIdx.x * 256 + threadIdx.x;
  if (i < 1024) stats[i] = 0.0f;
  if (i >= 73728) return;
  int j = i & 7;
  int co = (i >> 3) & 127;
  int th = i >> 10;                 // [0,72)
  int half = th & 1, ks = (th >> 1) & 3, tap = th >> 3;
  int kh = tap / 3, kw = tap - 3 * kh;
  int cin = ks * 16 + half * 8 + j;
  float v = w[((co * CINC + cin) * 3 + kh) * 3 + kw];
  wt2[i] = (unsigned short)f2bf(v);
}

// ---- conv implicit-GEMM ----
// grid: (64 tiles = 8 th x 8 tw, 32 batch), block 256 = 4 waves.
// Block tile 256 px (16x16) x 128 co; wave = 64 px x 128 co (mt2 x nt4).
// R3: weights staged per HALF-TAP (8 KB) via global_load_lds into a 4-slot LDS
// ring (32 KB). DMA for half-tap j issues 2 iterations early; each iteration
// ends with a COUNTED s_waitcnt vmcnt(2) + raw s_barrier -- one half-tap stays
// in flight across every barrier (never a vmcnt(0) drain; cf. R0's
// __syncthreads-per-tap which drained the pipeline 9x per block).
// Tap order is ROTATED per block ((bx+by)%9; conv sum is order-independent) so
// resident blocks spread their DMA bursts over 9 distinct 16 KB weight regions
// instead of all hitting the same hot L2 lines (R2 showed per-step hot-line
// latency dominating). setprio(1) wraps each 8-MFMA cluster (T5).
// Occupancy reg-capped at 2 blocks/CU (acc=128 AGPRs); LDS 74240 B also = 2.
// Pooled epilogue reuses x_lds. Raw-max-before-affine valid: A>0.
__global__ __launch_bounds__(256, 2) void conv_k(const float* __restrict__ x,
                                                 const unsigned short* __restrict__ wt2,
                                                 const float* __restrict__ conv_b,
                                                 float* __restrict__ out,
                                                 float* __restrict__ stats) {
  __shared__ __align__(16) unsigned int x_lds[18 * 18 * 32];  // 41472 B, XOR-swizzled
  __shared__ __align__(16) unsigned int aux_lds[8192];        // 32768 B: 4x2048 dw ring

  int t = threadIdx.x;
  int lane = t & 63, wave = t >> 6;
  int tw = blockIdx.x & 7, th = blockIdx.x >> 3;
  int b = blockIdx.y;
  int oh0 = th * 16, ow0 = tw * 16;
  int half = lane >> 5, m = lane & 31;

  int rot = (blockIdx.x + b) % 9;   // per-block tap rotation
  const unsigned int* wg = (const unsigned int*)wt2;  // dword view

  // DMA for half-tap j of the rotated sequence -> ring slot j&3.
  // Per wave: 2 loads x (64 lanes x 16 B) = 2 KB; block covers the full 8 KB.
#define DMA_HALFTAP(j)                                                         \
  {                                                                            \
    int tapj = rot + ((j) >> 1);                                               \
    if (tapj >= 9) tapj -= 9;                                                  \
    int srcb = (tapj * 2 + ((j)&1)) * 2048;                                    \
    int slot = (j)&3;                                                          \
    _Pragma("unroll")                                                          \
    for (int jj = 0; jj < 2; ++jj) {                                           \
      int dof = jj * 1024 + wave * 256;                                        \
      __builtin_amdgcn_global_load_lds(AS1U(wg + srcb + dof + lane * 4),       \
                                       AS3U(&aux_lds[slot * 2048 + dof]), 16,  \
                                       0, 0);                                  \
    }                                                                          \
  }

  // prologue: half-taps 0,1 in flight; they complete at the staging barrier
  DMA_HALFTAP(0)
  DMA_HALFTAP(1)

  float bias[4];
#pragma unroll
  for (int nt = 0; nt < 4; ++nt) bias[nt] = conv_b[nt * 32 + m];

  // ---- x staging: fp32 NCHW -> bf16 ci-pair dwords, swizzle d = p ^ ((c&7)<<2) ----
  const float* xb = x + (size_t)b * CINC * HIN * WIN;
#pragma unroll
  for (int k = 0; k < 12; ++k) {
    int i = k * 256 + t;
    if (i < 2880) {            // 5 c4 x 32 cipair x 18 r
      int c4 = i % 5;
      int j = i / 5;
      int p = j & 31;          // cipair: ci = 2p, 2p+1
      int r = j >> 5;          // 0..17
      int gr = oh0 + r;
      int gc0 = ow0 + c4 * 4;
      float4 v0 = make_float4(0.f, 0.f, 0.f, 0.f);
      float4 v1 = v0;
      if (gr < HIN && gc0 < WIN) {
        const float* base = xb + ((size_t)(2 * p) * HIN + gr) * WIN + gc0;
        v0 = *(const float4*)base;
        v1 = *(const float4*)(base + HIN * WIN);
      }
      float e0[4] = {v0.x, v0.y, v0.z, v0.w};
      float e1[4] = {v1.x, v1.y, v1.z, v1.w};
#pragma unroll
      for (int cc = 0; cc < 4; ++cc) {
        int c = c4 * 4 + cc;
        if (c < 18) {
          unsigned int d = f2bf(e0[cc]) | (f2bf(e1[cc]) << 16);
          x_lds[(r * 18 + c) * 32 + (p ^ ((c & 7) << 2))] = d;
        }
      }
    }
  }
  __syncthreads();   // x ready + half-taps 0,1 landed (full drain, once)

  // ---- MFMA main loop: 18 half-tap iterations, counted-vmcnt ring ----
  f32x16 acc[2][4];
#pragma unroll
  for (int nt = 0; nt < 4; ++nt)
#pragma unroll
    for (int mt = 0; mt < 2; ++mt)
#pragma unroll
      for (int r = 0; r < 16; ++r) acc[mt][nt][r] = bias[nt];

  int prb = wave * 4 + (m >> 4);   // + mt*2 + kh  -> pixel row in 18
  int pcc = m & 15;                // + kw         -> pixel col in 18

#pragma unroll
  for (int i = 0; i < 18; ++i) {
    if (i + 2 < 18) DMA_HALFTAP(i + 2)   // 2 loads -> in-flight joins prev 2

    int tap = rot + (i >> 1);
    if (tap >= 9) tap -= 9;
    int kh = (tap * 11) >> 5;            // tap/3 for 0..8
    int kw = tap - 3 * kh;
    int c = pcc + kw;
    int swz = (c & 7) << 2;
    int slot = i & 3;
    int hp = i & 1;
#pragma unroll
    for (int ks2 = 0; ks2 < 2; ++ks2) {
      int ks = hp * 2 + ks2;
      int ab = c * 32 + ((ks * 8 + half * 4) ^ swz);
      bf16x8 afr[2];
#pragma unroll
      for (int mt = 0; mt < 2; ++mt)
        afr[mt] = __builtin_bit_cast(
            bf16x8, *(const uint4*)&x_lds[(prb + mt * 2 + kh) * 576 + ab]);
      int wbase = slot * 2048 + ks2 * 1024 + half * 512 + m * 4;
      __builtin_amdgcn_s_setprio(1);
#pragma unroll
      for (int nt = 0; nt < 4; ++nt) {
        bf16x8 bfr =
            __builtin_bit_cast(bf16x8, *(const uint4*)&aux_lds[wbase + nt * 128]);
#pragma unroll
        for (int mt = 0; mt < 2; ++mt)
          acc[mt][nt] = __builtin_amdgcn_mfma_f32_32x32x16_bf16(
              afr[mt], bfr, acc[mt][nt], 0, 0, 0);
      }
      __builtin_amdgcn_s_setprio(0);
    }
    // counted wait: keep the newest half-tap's 2 loads in flight across the
    // barrier; only require the NEXT iteration's slot to be complete.
    if (i < 16) {
      asm volatile("s_waitcnt vmcnt(2)" ::: "memory");
    } else if (i == 16) {
      asm volatile("s_waitcnt vmcnt(0)" ::: "memory");
    }
    if (i < 17) {
      __builtin_amdgcn_s_barrier();
      __builtin_amdgcn_sched_barrier(0);   // pin: no ds_read drifts across
    }
  }
#undef DMA_HALFTAP

  // ---- GN partial sums (verified C/D mapping: row=pixel, col=cout) ----
  float s[4] = {0.f, 0.f, 0.f, 0.f}, qs[4] = {0.f, 0.f, 0.f, 0.f};
#pragma unroll
  for (int nt = 0; nt < 4; ++nt) {
#pragma unroll
    for (int mt = 0; mt < 2; ++mt) {
#pragma unroll
      for (int reg = 0; reg < 16; ++reg) {
        int c16 = (reg & 3) + 4 * half + 8 * ((reg >> 2) & 1);  // pixel col in 16
        int r8 = wave * 4 + mt * 2 + (reg >> 3);                // pixel row in 16
        if ((oh0 + r8) < HO && (ow0 + c16) < WO) {
          float v = acc[mt][nt][reg];
          s[nt] += v;
          qs[nt] += v * v;
        }
      }
    }
  }
#pragma unroll
  for (int nt = 0; nt < 4; ++nt) {
    float sv = s[nt], qv = qs[nt];
    sv += __shfl_xor(sv, 32);
    qv += __shfl_xor(qv, 32);
    sv += __shfl_down(sv, 4, 8);
    qv += __shfl_down(qv, 4, 8);
    sv += __shfl_down(sv, 2, 8);
    qv += __shfl_down(qv, 2, 8);
    sv += __shfl_down(sv, 1, 8);
    qv += __shfl_down(qv, 1, 8);
    if (half == 0 && (m & 7) == 0) {
      int g = nt * 4 + (m >> 3);
      atomicAdd(&stats[(b * NG + g) * 2 + 0], sv);
      atomicAdd(&stats[(b * NG + g) * 2 + 1], qv);
    }
  }

  __syncthreads();   // all waves done reading x_lds -> safe to reuse for pooled

  // ---- pooled 2x2 raw max -> x_lds (stride 66 dw/co: 2-way banks, free) ----
#pragma unroll
  for (int nt = 0; nt < 4; ++nt) {
    int co = nt * 32 + m;
#pragma unroll
    for (int mt = 0; mt < 2; ++mt) {
      int oh2l = wave * 2 + mt;
#pragma unroll
      for (int i = 0; i < 4; ++i) {
        int r0 = 2 * i;
        int ow2l = (i & 1) + 2 * half + 4 * (i >> 1);
        float mx = fmaxf(fmaxf(acc[mt][nt][r0], acc[mt][nt][r0 + 1]),
                         fmaxf(acc[mt][nt][r0 + 8], acc[mt][nt][r0 + 9]));
        x_lds[co * 66 + oh2l * 8 + ow2l] = __float_as_uint(mx);
      }
    }
  }
  __syncthreads();

  // ---- readback: 4 rows/thread, 8 consecutive dwords per row ----
#pragma unroll
  for (int i = 0; i < 4; ++i) {
    int row = t * 4 + i;           // row = co*8 + oh2l
    int co = row >> 3, oh2l = row & 7;
    int oh2 = th * 8 + oh2l;
    if (oh2 < HP) {
      const uint2* src = (const uint2*)&x_lds[co * 66 + oh2l * 8];
      uint2 d0 = src[0], d1 = src[1], d2 = src[2], d3 = src[3];
      unsigned int v[8] = {d0.x, d0.y, d1.x, d1.y, d2.x, d2.y, d3.x, d3.y};
      float* ob = out + ((size_t)(b * COUTC + co) * HP + oh2) * WP + tw * 8;
      int n = (tw == 7) ? 7 : 8;   // WP = 63
#pragma unroll
      for (int e = 0; e < 8; ++e)
        if (e < n) ob[e] = __uint_as_float(v[e]);
    }
  }
}

// ---- finalize: one block per (b,c) plane; A,B computed once, pure streaming ----
__global__ __launch_bounds__(256) void fin_k(float* __restrict__ out,
                                             const float* __restrict__ stats,
                                             const float* __restrict__ gn_w,
                                             const float* __restrict__ gn_b,
                                             const float* __restrict__ scale) {
  const int plane = HP * WP;                     // 3969 (odd -> plane bases rotate mod 4)
  const float inv_cnt = 1.0f / (8.0f * HO * WO);
  int bc = blockIdx.x;                           // b*128 + c, grid = 4096
  int c = bc & 127, b = bc >> 7;
  int g = c >> 3;
  float su = stats[(b * NG + g) * 2 + 0];
  float sq = stats[(b * NG + g) * 2 + 1];
  float mean = su * inv_cnt;
  float var = fmaxf(sq * inv_cnt - mean * mean, 0.f);
  float rstd = rsqrtf(var + 1e-5f);
  float gw = gn_w[c], sc = scale[c];
  float A = rstd * gw * sc;
  float Bo = (gn_b[c] - mean * rstd * gw) * sc;

  float* p = out + (size_t)bc * plane;
  int t = threadIdx.x;
  int head = (4 - (bc & 3)) & 3;                 // scalars until 16B-aligned
  if (t < head) p[t] = fminf(fmaxf(fmaf(p[t], A, Bo), 0.0f), 1.0f);
  int n4 = (plane - head) >> 2;
  float4* p4 = (float4*)(p + head);
  for (int i = t; i < n4; i += 256) {
    float4 v = p4[i];
    v.x = fminf(fmaxf(fmaf(v.x, A, Bo), 0.0f), 1.0f);
    v.y = fminf(fmaxf(fmaf(v.y, A, Bo), 0.0f), 1.0f);
    v.z = fminf(fmaxf(fmaf(v.z, A, Bo), 0.0f), 1.0f);
    v.w = fminf(fmaxf(fmaf(v.w, A, Bo), 0.0f), 1.0f);
    p4[i] = v;
  }
  int done = head + (n4 << 2);
  int tail = plane - done;                       // 0..3
  if (t < tail) p[done + t] = fminf(fmaxf(fmaf(p[done + t], A, Bo), 0.0f), 1.0f);
}

// ---- launch ----
extern "C" void kernel_launch(void* const* d_in, const int* in_sizes, int n_in,
                              void* d_out, int out_size, void* d_ws, size_t ws_size,
                              hipStream_t stream) {
  const float* x      = (const float*)d_in[0];
  const float* conv_w = (const float*)d_in[1];
  const float* conv_b = (const float*)d_in[2];
  const float* gn_w   = (const float*)d_in[3];
  const float* gn_b   = (const float*)d_in[4];
  const float* scale  = (const float*)d_in[5];
  float* out = (float*)d_out;

  float* stats        = (float*)d_ws;                           // 4 KB
  unsigned short* wt2 = (unsigned short*)((char*)d_ws + 4096);  // 147456 B

  wtrans_k<<<288, 256, 0, stream>>>(conv_w, wt2, stats);

  conv_k<<<dim3(64, NB), 256, 0, stream>>>(x, wt2, conv_b, out, stats);

  fin_k<<<4096, 256, 0, stream>>>(out, stats, gn_w, gn_b, scale);
}